// Round 23
// baseline (72.288 us; speedup 1.0000x reference)
//
#include <hip/hip_runtime.h>

#define NTOK 8192
#define NH 16
#define DD 64
#define NEGF -1e30f
#define LOG2E 1.4426950408889634f
#define CUT1 1024

typedef __attribute__((ext_vector_type(8))) short bf16x8;
typedef __attribute__((ext_vector_type(4))) float f32x4;

#define MFMA(a, b, c) __builtin_amdgcn_mfma_f32_16x16x32_bf16((a), (b), (c), 0, 0, 0)
#define EXP2(x) __builtin_amdgcn_exp2f(x)

static __device__ __forceinline__ unsigned short f2bf(float x) {
    union { float f; unsigned u; } c; c.f = x;
    unsigned r = (c.u + 0x7FFFu + ((c.u >> 16) & 1u)) >> 16;
    return (unsigned short)r;
}
static __device__ __forceinline__ float bf2f(unsigned short x) {
    union { unsigned u; float f; } c; c.u = ((unsigned)x) << 16;
    return c.f;
}

// ---------------- fused prep: k->BLOCKED bf16 + v->blocked vt + level-1 pool (k1, vt1) ----------------
__global__ __launch_bounds__(256) void prep_kv1(const float* __restrict__ k, const float* __restrict__ v,
                                                unsigned short* __restrict__ Kb,
                                                unsigned short* __restrict__ vt,
                                                unsigned short* __restrict__ k1,
                                                unsigned short* __restrict__ vt1) {
    int h = blockIdx.x >> 7;
    int n0 = (blockIdx.x & 127) << 6;
    int tid = threadIdx.x;
    __shared__ unsigned short t[64][65];

    // ---- Phase A: V -> LDS (transposed) ----
    {
        int col = tid & 63;
        int rr = tid >> 6;
        const float* src = v + ((size_t)(h * NTOK + n0)) * DD;
#pragma unroll
        for (int r = 0; r < 16; ++r) {
            int row = rr + r * 4;
            t[col][row] = f2bf(src[(size_t)row * DD + col]);
        }
    }
    __syncthreads();
    {
        int d = tid >> 2, ch = tid & 3;
        union { unsigned short u[16]; uint4 q[2]; } tmp;
#pragma unroll
        for (int j = 0; j < 16; ++j) tmp.u[j] = t[d][ch * 16 + j];
        int b = (n0 >> 5) + (ch >> 1);
        unsigned short* dst = vt + ((size_t)(h * 256 + b)) * 2048 + d * 32 + (ch & 1) * 16;
        ((uint4*)dst)[0] = tmp.q[0];
        ((uint4*)dst)[1] = tmp.q[1];
    }
    {
        int dd = tid & 63;
        int cc = tid >> 6;
#pragma unroll
        for (int u = 0; u < 2; ++u) {
            int c8 = cc + u * 4;
            float s = 0.f;
#pragma unroll
            for (int r = 0; r < 8; ++r) s += bf2f(t[dd][8 * c8 + r]);
            int C = (n0 >> 3) + c8;
            vt1[((size_t)((h * 32 + (C >> 5)) * DD + dd)) * 32 + (C & 31)] = f2bf(s * 0.125f);
        }
    }
    __syncthreads();

    // ---- Phase B: K convert -> blocked Kb + LDS ----
    {
        int row = tid >> 2, cs = (tid & 3) * 16;
        const float* src = k + ((size_t)(h * NTOK + n0 + row)) * DD + cs;
        float4 f0 = ((const float4*)src)[0], f1 = ((const float4*)src)[1];
        float4 f2 = ((const float4*)src)[2], f3 = ((const float4*)src)[3];
        union { unsigned short u[16]; uint4 q4[2]; } o;
        o.u[0] = f2bf(f0.x); o.u[1] = f2bf(f0.y); o.u[2] = f2bf(f0.z); o.u[3] = f2bf(f0.w);
        o.u[4] = f2bf(f1.x); o.u[5] = f2bf(f1.y); o.u[6] = f2bf(f1.z); o.u[7] = f2bf(f1.w);
        o.u[8] = f2bf(f2.x); o.u[9] = f2bf(f2.y); o.u[10] = f2bf(f2.z); o.u[11] = f2bf(f2.w);
        o.u[12] = f2bf(f3.x); o.u[13] = f2bf(f3.y); o.u[14] = f2bf(f3.z); o.u[15] = f2bf(f3.w);
        int grpb = (n0 >> 5) + (row >> 5);
        int kk = row & 31;
        int cw = ((kk >> 3) << 2) | (kk & 3);
        int qd = ((kk >> 2) & 1) * 2 + (cs >= 32 ? 1 : 0);
        int g0w = (cs & 31) >> 3;
        unsigned short* blk = Kb + ((size_t)(h * 256 + grpb)) * 2048 + qd * 512;
        *(uint4*)(blk + (g0w * 16 + cw) * 8) = o.q4[0];
        *(uint4*)(blk + ((g0w + 1) * 16 + cw) * 8) = o.q4[1];
#pragma unroll
        for (int j = 0; j < 16; ++j) t[cs + j][row] = o.u[j];
    }
    __syncthreads();
    {
        int dd = tid & 63;
        int cc = tid >> 6;
#pragma unroll
        for (int u = 0; u < 2; ++u) {
            int c8 = cc + u * 4;
            float s = 0.f;
#pragma unroll
            for (int r = 0; r < 8; ++r) s += bf2f(t[dd][8 * c8 + r]);
            int C = (n0 >> 3) + c8;
            k1[((size_t)(h * 1024 + C)) * DD + dd] = f2bf(s * 0.125f);
        }
    }
}

// ---------------- level-2 pool ----------------
__global__ __launch_bounds__(256) void pool2_b(const unsigned short* __restrict__ k1,
                                               const unsigned short* __restrict__ vt1,
                                               unsigned short* __restrict__ k2,
                                               unsigned short* __restrict__ vt2) {
    int tid = blockIdx.x * blockDim.x + threadIdx.x;
    int d = tid & 63;
    int c = (tid >> 6) & 127;
    int h = tid >> 13;
    const unsigned short* kp = k1 + ((size_t)(h * 1024 + c * 8)) * DD + d;
    float ks = 0.f;
#pragma unroll
    for (int r = 0; r < 8; ++r) ks += bf2f(kp[(size_t)r * DD]);
    const unsigned short* vp = vt1 + ((size_t)((h * 32 + (c >> 2)) * DD + d)) * 32 + 8 * (c & 3);
    union { unsigned short u[8]; uint4 q; } vv;
    vv.q = *(const uint4*)(const void*)vp;
    float vs = 0.f;
#pragma unroll
    for (int j = 0; j < 8; ++j) vs += bf2f(vv.u[j]);
    k2[((size_t)(h * 128 + c)) * DD + d] = f2bf(ks * 0.125f);
    vt2[((size_t)((h * 4 + (c >> 5)) * DD + d)) * 32 + (c & 31)] = f2bf(vs * 0.125f);
}

// ---------------- level-3 pool (16 real chunks, padded to 32) ----------------
__global__ __launch_bounds__(256) void pool3_b(const unsigned short* __restrict__ k2,
                                               const unsigned short* __restrict__ vt2,
                                               unsigned short* __restrict__ k3,
                                               unsigned short* __restrict__ vt3) {
    int tid = blockIdx.x * blockDim.x + threadIdx.x;
    int d = tid & 63;
    int c = (tid >> 6) & 31;
    int h = tid >> 11;
    float ks = 0.f, vs = 0.f;
    if (c < 16) {
        const unsigned short* kp = k2 + ((size_t)(h * 128 + c * 8)) * DD + d;
#pragma unroll
        for (int r = 0; r < 8; ++r) ks += bf2f(kp[(size_t)r * DD]);
        const unsigned short* vp = vt2 + ((size_t)((h * 4 + (c >> 2)) * DD + d)) * 32 + 8 * (c & 3);
        union { unsigned short u[8]; uint4 q; } vv;
        vv.q = *(const uint4*)(const void*)vp;
#pragma unroll
        for (int j = 0; j < 8; ++j) vs += bf2f(vv.u[j]);
        ks *= 0.125f; vs *= 0.125f;
    }
    k3[((size_t)(h * 32 + c)) * DD + d] = f2bf(ks);
    vt3[((size_t)(h * DD + d)) * 32 + c] = f2bf(vs);
}

// K+V fragments of one 32-key group
struct KV32 { bf16x8 k0, k1, k2, k3, v0, v1, v2, v3; };

// ---------------- one 32-key sub-group, 32 queries (2 tiles) ----------------
// Fixed-m streaming: no per-group max/ballot/rescale. INIT computes m once.
template<bool L0T, bool INIT>
__device__ __forceinline__ void sub32(
    int c0, int Qs, int lgS, float gp, float gps, float& m,
    const KV32& t, int g, int c,
    bf16x8 qa0, bf16x8 qa1, bf16x8 qb0, bf16x8 qb1,
    float& lA, float& lB, f32x4* oA, f32x4* oB)
{
    const int i_qA = Qs + c, i_qB = i_qA + 16;

    __builtin_amdgcn_s_setprio(1);
    f32x4 z = {0.f, 0.f, 0.f, 0.f};
    f32x4 sAA = MFMA(t.k1, qa1, MFMA(t.k0, qa0, z));
    f32x4 sAB = MFMA(t.k3, qa1, MFMA(t.k2, qa0, z));
    f32x4 sBA = MFMA(t.k1, qb1, MFMA(t.k0, qb0, z));
    f32x4 sBB = MFMA(t.k3, qb1, MFMA(t.k2, qb0, z));
    __builtin_amdgcn_s_setprio(0);

    const float negfbA = gps * (float)(8 * g) + gp * (float)((1 << lgS) - 1) - gp * (float)i_qA;
    const float negfbB = negfbA - 16.f * gp;
    float c0f = (float)c0;

    float svA[8], svB[8];
    bool fastA, fastB;
    if (L0T) {
        fastA = (c0 >= Qs - 112) && (c0 + 31 <= Qs);
        fastB = (c0 >= Qs - 96) && (c0 + 31 <= Qs + 16);
    } else {
        int numA = Qs - 128 - ((1 << lgS) - 1);
        int numB = numA + 16;
        fastA = (numA >= 0) && (c0 + 31 <= (numA >> lgS));
        fastB = (numB >= 0) && (c0 + 31 <= (numB >> lgS));
    }
    if (fastA) {
        float u0 = fmaf(gps, c0f, negfbA);
        svA[0] = sAA[0] + u0;
        svA[1] = sAA[1] + fmaf(gps, 1.f, u0);
        svA[2] = sAA[2] + fmaf(gps, 2.f, u0);
        svA[3] = sAA[3] + fmaf(gps, 3.f, u0);
        svA[4] = sAB[0] + fmaf(gps, 4.f, u0);
        svA[5] = sAB[1] + fmaf(gps, 5.f, u0);
        svA[6] = sAB[2] + fmaf(gps, 6.f, u0);
        svA[7] = sAB[3] + fmaf(gps, 7.f, u0);
    } else {
#pragma unroll
        for (int r = 0; r < 4; ++r) {
            int cA = c0 + 8 * g + r, cB = cA + 4;
            int jA = L0T ? cA : (((cA + 1) << lgS) - 1);
            int jB = L0T ? cB : (((cB + 1) << lgS) - 1);
            int dA = i_qA - jA, dB = i_qA - jB;
            bool aA = L0T ? ((unsigned)dA <= 127u) : (dA >= 128);
            bool aB = L0T ? ((unsigned)dB <= 127u) : (dB >= 128);
            svA[r]     = aA ? fmaf(-gp, (float)dA, sAA[r]) : NEGF;
            svA[r + 4] = aB ? fmaf(-gp, (float)dB, sAB[r]) : NEGF;
        }
    }
    if (fastB) {
        float u0 = fmaf(gps, c0f, negfbB);
        svB[0] = sBA[0] + u0;
        svB[1] = sBA[1] + fmaf(gps, 1.f, u0);
        svB[2] = sBA[2] + fmaf(gps, 2.f, u0);
        svB[3] = sBA[3] + fmaf(gps, 3.f, u0);
        svB[4] = sBB[0] + fmaf(gps, 4.f, u0);
        svB[5] = sBB[1] + fmaf(gps, 5.f, u0);
        svB[6] = sBB[2] + fmaf(gps, 6.f, u0);
        svB[7] = sBB[3] + fmaf(gps, 7.f, u0);
    } else {
#pragma unroll
        for (int r = 0; r < 4; ++r) {
            int cA = c0 + 8 * g + r, cB = cA + 4;
            int jA = L0T ? cA : (((cA + 1) << lgS) - 1);
            int jB = L0T ? cB : (((cB + 1) << lgS) - 1);
            int dA = i_qB - jA, dB = i_qB - jB;
            bool aA = L0T ? ((unsigned)dA <= 127u) : (dA >= 128);
            bool aB = L0T ? ((unsigned)dB <= 127u) : (dB >= 128);
            svB[r]     = aA ? fmaf(-gp, (float)dA, sBA[r]) : NEGF;
            svB[r + 4] = aB ? fmaf(-gp, (float)dB, sBB[r]) : NEGF;
        }
    }

    if (INIT) {
        float tm = fmaxf(
            fmaxf(fmaxf(fmaxf(svA[0], svA[1]), fmaxf(svA[2], svA[3])),
                  fmaxf(fmaxf(svA[4], svA[5]), fmaxf(svA[6], svA[7]))),
            fmaxf(fmaxf(fmaxf(svB[0], svB[1]), fmaxf(svB[2], svB[3])),
                  fmaxf(fmaxf(svB[4], svB[5]), fmaxf(svB[6], svB[7]))));
        tm = fmaxf(tm, __shfl_xor(tm, 1));
        tm = fmaxf(tm, __shfl_xor(tm, 2));
        tm = fmaxf(tm, __shfl_xor(tm, 4));
        tm = fmaxf(tm, __shfl_xor(tm, 8));
        tm = fmaxf(tm, __shfl_xor(tm, 16));
        tm = fmaxf(tm, __shfl_xor(tm, 32));
        m = tm;
    }

    union { unsigned u32[4]; bf16x8 v8; } pfA, pfB;
    {
        float p[8];
#pragma unroll
        for (int r = 0; r < 8; ++r) p[r] = EXP2(svA[r] - m);
        lA += ((p[0] + p[1]) + (p[2] + p[3])) + ((p[4] + p[5]) + (p[6] + p[7]));
#pragma unroll
        for (int j = 0; j < 4; ++j)
            asm("v_cvt_pk_bf16_f32 %0, %1, %2" : "=v"(pfA.u32[j]) : "v"(p[2 * j]), "v"(p[2 * j + 1]));
    }
    {
        float p[8];
#pragma unroll
        for (int r = 0; r < 8; ++r) p[r] = EXP2(svB[r] - m);
        lB += ((p[0] + p[1]) + (p[2] + p[3])) + ((p[4] + p[5]) + (p[6] + p[7]));
#pragma unroll
        for (int j = 0; j < 4; ++j)
            asm("v_cvt_pk_bf16_f32 %0, %1, %2" : "=v"(pfB.u32[j]) : "v"(p[2 * j]), "v"(p[2 * j + 1]));
    }

    __builtin_amdgcn_s_setprio(1);
    oA[0] = MFMA(t.v0, pfA.v8, oA[0]);
    oB[0] = MFMA(t.v0, pfB.v8, oB[0]);
    oA[1] = MFMA(t.v1, pfA.v8, oA[1]);
    oB[1] = MFMA(t.v1, pfB.v8, oB[1]);
    oA[2] = MFMA(t.v2, pfA.v8, oA[2]);
    oB[2] = MFMA(t.v2, pfB.v8, oB[2]);
    oA[3] = MFMA(t.v3, pfA.v8, oA[3]);
    oB[3] = MFMA(t.v3, pfB.v8, oB[3]);
    __builtin_amdgcn_s_setprio(0);
}

// ---------------- main attention: 1 wave/block (32 queries), LPT, blocked L0 K ----------------
__global__ __launch_bounds__(64, 2) void attn_mfma(
    const float* __restrict__ q, const unsigned short* __restrict__ Kb,
    const unsigned short* __restrict__ Vtb,
    const unsigned short* __restrict__ K1, const unsigned short* __restrict__ Vt1,
    const unsigned short* __restrict__ K2, const unsigned short* __restrict__ Vt2,
    const unsigned short* __restrict__ K3, const unsigned short* __restrict__ Vt3,
    const float* __restrict__ gam, float* __restrict__ out) {
    const int lane = threadIdx.x;
    const int h = blockIdx.x & 15;            // head->XCD pinning for L2 locality
    const int qpos = 255 - (blockIdx.x >> 4); // LPT: heaviest (late) positions dispatch first
    const int Qs = qpos << 5;
    const int g = lane >> 4;
    const int c = lane & 15;

    const float g0 = gam[0] * LOG2E, g1 = gam[1] * LOG2E;
    const float g2 = gam[2] * LOG2E, g3 = gam[3] * LOG2E;

    // L0: blocked K + blocked V
    const unsigned short* KbB = Kb + (size_t)h * 256 * 2048 + lane * 8;
    const unsigned short* VtH = Vtb + (size_t)h * 256 * 2048 + c * 32 + g * 8;
    // pooled levels: row-major K (key-permuted) + blocked V
    const size_t kperm = ((size_t)(8 * (c >> 2) + (c & 3))) * DD + g * 8;
    const unsigned short* K1H = K1 + (size_t)h * 1024 * DD + kperm;
    const unsigned short* V1H = Vt1 + (size_t)h * 32 * 2048 + c * 32 + g * 8;
    const unsigned short* K2H = K2 + (size_t)h * 128 * DD + kperm;
    const unsigned short* V2H = Vt2 + (size_t)h * 4 * 2048 + c * 32 + g * 8;
    const unsigned short* K3H = K3 + (size_t)h * 32 * DD + kperm;
    const unsigned short* V3H = Vt3 + (size_t)h * 2048 + c * 32 + g * 8;

    auto LOADKV0 = [&](int c0) -> KV32 {   // L0: fully blocked (8 contiguous 1KB loads)
        KV32 r;
        const unsigned short* ka = KbB + (size_t)(c0 >> 5) * 2048;
        r.k0 = *(const bf16x8*)(const void*)(ka);
        r.k1 = *(const bf16x8*)(const void*)(ka + 512);
        r.k2 = *(const bf16x8*)(const void*)(ka + 1024);
        r.k3 = *(const bf16x8*)(const void*)(ka + 1536);
        const unsigned short* va = VtH + (size_t)(c0 >> 5) * 2048;
        r.v0 = *(const bf16x8*)(const void*)(va);
        r.v1 = *(const bf16x8*)(const void*)(va + 512);
        r.v2 = *(const bf16x8*)(const void*)(va + 1024);
        r.v3 = *(const bf16x8*)(const void*)(va + 1536);
        return r;
    };
    auto LOADKV = [&](const unsigned short* Kh, const unsigned short* Vh, int c0) -> KV32 {
        KV32 r;
        const unsigned short* ka = Kh + (size_t)c0 * DD;
        r.k0 = *(const bf16x8*)(const void*)(ka);
        r.k1 = *(const bf16x8*)(const void*)(ka + 32);
        r.k2 = *(const bf16x8*)(const void*)(ka + 4 * DD);
        r.k3 = *(const bf16x8*)(const void*)(ka + 4 * DD + 32);
        const unsigned short* va = Vh + (size_t)(c0 >> 5) * 2048;
        r.v0 = *(const bf16x8*)(const void*)(va);
        r.v1 = *(const bf16x8*)(const void*)(va + 512);
        r.v2 = *(const bf16x8*)(const void*)(va + 1024);
        r.v3 = *(const bf16x8*)(const void*)(va + 1536);
        return r;
    };

    // Q fragments: fp32 load + scale + pack to bf16 in-kernel
    const float qsc = 0.125f * LOG2E;
    bf16x8 qa0, qa1, qb0, qb1;
    {
        const float* qrA = q + ((size_t)(h * NTOK + Qs + c)) * DD;
        const float* qrB = qrA + 16 * DD;
        float4 a0 = *(const float4*)(qrA + g * 8),      a1 = *(const float4*)(qrA + g * 8 + 4);
        float4 a2 = *(const float4*)(qrA + 32 + g * 8), a3 = *(const float4*)(qrA + 32 + g * 8 + 4);
        float4 b0 = *(const float4*)(qrB + g * 8),      b1 = *(const float4*)(qrB + g * 8 + 4);
        float4 b2 = *(const float4*)(qrB + 32 + g * 8), b3 = *(const float4*)(qrB + 32 + g * 8 + 4);
        union { unsigned u32[4]; bf16x8 v8; } p0, p1, p2, p3;
        asm("v_cvt_pk_bf16_f32 %0, %1, %2" : "=v"(p0.u32[0]) : "v"(a0.x * qsc), "v"(a0.y * qsc));
        asm("v_cvt_pk_bf16_f32 %0, %1, %2" : "=v"(p0.u32[1]) : "v"(a0.z * qsc), "v"(a0.w * qsc));
        asm("v_cvt_pk_bf16_f32 %0, %1, %2" : "=v"(p0.u32[2]) : "v"(a1.x * qsc), "v"(a1.y * qsc));
        asm("v_cvt_pk_bf16_f32 %0, %1, %2" : "=v"(p0.u32[3]) : "v"(a1.z * qsc), "v"(a1.w * qsc));
        asm("v_cvt_pk_bf16_f32 %0, %1, %2" : "=v"(p1.u32[0]) : "v"(a2.x * qsc), "v"(a2.y * qsc));
        asm("v_cvt_pk_bf16_f32 %0, %1, %2" : "=v"(p1.u32[1]) : "v"(a2.z * qsc), "v"(a2.w * qsc));
        asm("v_cvt_pk_bf16_f32 %0, %1, %2" : "=v"(p1.u32[2]) : "v"(a3.x * qsc), "v"(a3.y * qsc));
        asm("v_cvt_pk_bf16_f32 %0, %1, %2" : "=v"(p1.u32[3]) : "v"(a3.z * qsc), "v"(a3.w * qsc));
        asm("v_cvt_pk_bf16_f32 %0, %1, %2" : "=v"(p2.u32[0]) : "v"(b0.x * qsc), "v"(b0.y * qsc));
        asm("v_cvt_pk_bf16_f32 %0, %1, %2" : "=v"(p2.u32[1]) : "v"(b0.z * qsc), "v"(b0.w * qsc));
        asm("v_cvt_pk_bf16_f32 %0, %1, %2" : "=v"(p2.u32[2]) : "v"(b1.x * qsc), "v"(b1.y * qsc));
        asm("v_cvt_pk_bf16_f32 %0, %1, %2" : "=v"(p2.u32[3]) : "v"(b1.z * qsc), "v"(b1.w * qsc));
        asm("v_cvt_pk_bf16_f32 %0, %1, %2" : "=v"(p3.u32[0]) : "v"(b2.x * qsc), "v"(b2.y * qsc));
        asm("v_cvt_pk_bf16_f32 %0, %1, %2" : "=v"(p3.u32[1]) : "v"(b2.z * qsc), "v"(b2.w * qsc));
        asm("v_cvt_pk_bf16_f32 %0, %1, %2" : "=v"(p3.u32[2]) : "v"(b3.x * qsc), "v"(b3.y * qsc));
        asm("v_cvt_pk_bf16_f32 %0, %1, %2" : "=v"(p3.u32[3]) : "v"(b3.z * qsc), "v"(b3.w * qsc));
        qa0 = p0.v8; qa1 = p1.v8; qb0 = p2.v8; qb1 = p3.v8;
    }

    f32x4 oA[4], oB[4];
#pragma unroll
    for (int t = 0; t < 4; ++t) { oA[t] = (f32x4){0.f,0.f,0.f,0.f}; oB[t] = (f32x4){0.f,0.f,0.f,0.f}; }
    float m = NEGF, lA = 0.f, lB = 0.f;

    // ---- level 0, diagonal group (INIT m) ----
    {
        KV32 t = LOADKV0(Qs);
        sub32<true, true>(Qs, Qs, 0, g0, g0, m, t, g, c, qa0, qa1, qb0, qb1, lA, lB, oA, oB);
    }
    // ---- level 0, remaining window, paired 64-key iterations ----
    {
        int lo0 = Qs - 127; if (lo0 < 0) lo0 = 0; lo0 &= ~31;
        int c0 = Qs - 64;
        while (c0 >= lo0) {
            KV32 a = LOADKV0(c0 + 32);
            KV32 b = LOADKV0(c0);
            sub32<true, false>(c0 + 32, Qs, 0, g0, g0, m, a, g, c, qa0, qa1, qb0, qb1, lA, lB, oA, oB);
            sub32<true, false>(c0,      Qs, 0, g0, g0, m, b, g, c, qa0, qa1, qb0, qb1, lA, lB, oA, oB);
            c0 -= 64;
        }
        if (c0 + 32 >= lo0) {
            KV32 a = LOADKV0(c0 + 32);
            sub32<true, false>(c0 + 32, Qs, 0, g0, g0, m, a, g, c, qa0, qa1, qb0, qb1, lA, lB, oA, oB);
        }
    }
    // ---- level 1: 64-key iterations, truncated at CUT1 tokens ----
    {
        int cm = Qs - 104;                 // (Qs+31)-128-7
        if (cm >= 0) {
            int top = (cm >> 3) & ~31;
            int lo = Qs - CUT1;
            lo = (lo <= 0) ? 0 : ((lo >> 3) & ~31);
            int c0 = top;
            while (c0 - 32 >= lo) {
                KV32 a = LOADKV(K1H, V1H, c0);
                KV32 b = LOADKV(K1H, V1H, c0 - 32);
                sub32<false, false>(c0,      Qs, 3, g1, g1 * 8.f, m, a, g, c, qa0, qa1, qb0, qb1, lA, lB, oA, oB);
                sub32<false, false>(c0 - 32, Qs, 3, g1, g1 * 8.f, m, b, g, c, qa0, qa1, qb0, qb1, lA, lB, oA, oB);
                c0 -= 64;
            }
            if (c0 >= lo) {
                KV32 a = LOADKV(K1H, V1H, c0);
                sub32<false, false>(c0, Qs, 3, g1, g1 * 8.f, m, a, g, c, qa0, qa1, qb0, qb1, lA, lB, oA, oB);
            }
        }
    }
    // ---- level 2: 64-key iterations (<=2) ----
    {
        int cm = Qs - 160;                 // (Qs+31)-128-63
        if (cm >= 0) {
            for (int c0 = ((cm / 64) & ~63); c0 >= 0; c0 -= 64) {
                KV32 a = LOADKV(K2H, V2H, c0 + 32);
                KV32 b = LOADKV(K2H, V2H, c0);
                sub32<false, false>(c0 + 32, Qs, 6, g2, g2 * 64.f, m, a, g, c, qa0, qa1, qb0, qb1, lA, lB, oA, oB);
                sub32<false, false>(c0,      Qs, 6, g2, g2 * 64.f, m, b, g, c, qa0, qa1, qb0, qb1, lA, lB, oA, oB);
            }
        }
    }
    // ---- level 3: single 32-chunk group ----
    {
        if (Qs >= 608) {
            KV32 t = LOADKV(K3H, V3H, 0);
            sub32<false, false>(0, Qs, 9, g3, g3 * 512.f, m, t, g, c, qa0, qa1, qb0, qb1, lA, lB, oA, oB);
        }
    }

    // final l reduce over the 4 g-lanes of each query column
    float ltA = lA + __shfl_xor(lA, 16); ltA += __shfl_xor(ltA, 32);
    float ltB = lB + __shfl_xor(lB, 16); ltB += __shfl_xor(ltB, 32);
    float invA = 1.0f / fmaxf(ltA, 1e-8f);
    float invB = 1.0f / fmaxf(ltB, 1e-8f);

    float* orowA = out + ((size_t)(h * NTOK + Qs + c)) * DD;
    float* orowB = orowA + 16 * DD;
#pragma unroll
    for (int db = 0; db < 4; ++db) {
        float4 x;
        x.x = oA[db][0] * invA; x.y = oA[db][1] * invA;
        x.z = oA[db][2] * invA; x.w = oA[db][3] * invA;
        *(float4*)(orowA + db * 16 + 4 * g) = x;
        float4 y;
        y.x = oB[db][0] * invB; y.y = oB[db][1] * invB;
        y.z = oB[db][2] * invB; y.w = oB[db][3] * invB;
        *(float4*)(orowB + db * 16 + 4 * g) = y;
    }
}

extern "C" void kernel_launch(void* const* d_in, const int* in_sizes, int n_in,
                              void* d_out, int out_size, void* d_ws, size_t ws_size,
                              hipStream_t stream) {
    const float* q = (const float*)d_in[0];
    const float* k = (const float*)d_in[1];
    const float* v = (const float*)d_in[2];
    const float* gam = (const float*)d_in[3];
    float* out = (float*)d_out;

    char* w = (char*)d_ws;
    const size_t bigN = (size_t)NH * NTOK * DD * sizeof(unsigned short);
    unsigned short* Kbuf = (unsigned short*)w;  w += bigN;
    unsigned short* Vtb  = (unsigned short*)w;  w += bigN;
    unsigned short* K1   = (unsigned short*)w;  w += (size_t)NH * 1024 * DD * 2;
    unsigned short* Vt1  = (unsigned short*)w;  w += (size_t)NH * 1024 * DD * 2;
    unsigned short* K2   = (unsigned short*)w;  w += (size_t)NH * 128 * DD * 2;
    unsigned short* Vt2  = (unsigned short*)w;  w += (size_t)NH * 128 * DD * 2;
    unsigned short* K3   = (unsigned short*)w;  w += (size_t)NH * 32 * DD * 2;
    unsigned short* Vt3  = (unsigned short*)w;  w += (size_t)NH * 32 * DD * 2;

    prep_kv1<<<NH * (NTOK / 64), 256, 0, stream>>>(k, v, Kbuf, Vtb, K1, Vt1);
    pool2_b<<<NH * 128 * DD / 256, 256, 0, stream>>>(K1, Vt1, K2, Vt2);
    pool3_b<<<NH * 32 * DD / 256, 256, 0, stream>>>(K2, Vt2, K3, Vt3);

    attn_mfma<<<NH * 256, 64, 0, stream>>>(q, Kbuf, Vtb, K1, Vt1, K2, Vt2, K3, Vt3, gam, out);
}

// Round 24
// 69.350 us; speedup vs baseline: 1.0424x; 1.0424x over previous
//
#include <hip/hip_runtime.h>

#define NTOK 8192
#define NH 16
#define DD 64
#define NEGF -1e30f
#define LOG2E 1.4426950408889634f
#define CUT1 896

typedef __attribute__((ext_vector_type(8))) short bf16x8;
typedef __attribute__((ext_vector_type(4))) float f32x4;

#define MFMA(a, b, c) __builtin_amdgcn_mfma_f32_16x16x32_bf16((a), (b), (c), 0, 0, 0)
#define EXP2(x) __builtin_amdgcn_exp2f(x)

static __device__ __forceinline__ unsigned short f2bf(float x) {
    union { float f; unsigned u; } c; c.f = x;
    unsigned r = (c.u + 0x7FFFu + ((c.u >> 16) & 1u)) >> 16;
    return (unsigned short)r;
}
static __device__ __forceinline__ float bf2f(unsigned short x) {
    union { unsigned u; float f; } c; c.u = ((unsigned)x) << 16;
    return c.f;
}

// ---------------- fused prep: k->BLOCKED bf16 + v->blocked vt + level-1 pool (k1, vt1) ----------------
__global__ __launch_bounds__(256) void prep_kv1(const float* __restrict__ k, const float* __restrict__ v,
                                                unsigned short* __restrict__ Kb,
                                                unsigned short* __restrict__ vt,
                                                unsigned short* __restrict__ k1,
                                                unsigned short* __restrict__ vt1) {
    int h = blockIdx.x >> 7;
    int n0 = (blockIdx.x & 127) << 6;
    int tid = threadIdx.x;
    __shared__ unsigned short t[64][65];

    // ---- Phase A: V -> LDS (transposed) ----
    {
        int col = tid & 63;
        int rr = tid >> 6;
        const float* src = v + ((size_t)(h * NTOK + n0)) * DD;
#pragma unroll
        for (int r = 0; r < 16; ++r) {
            int row = rr + r * 4;
            t[col][row] = f2bf(src[(size_t)row * DD + col]);
        }
    }
    __syncthreads();
    {
        int d = tid >> 2, ch = tid & 3;
        union { unsigned short u[16]; uint4 q[2]; } tmp;
#pragma unroll
        for (int j = 0; j < 16; ++j) tmp.u[j] = t[d][ch * 16 + j];
        int b = (n0 >> 5) + (ch >> 1);
        unsigned short* dst = vt + ((size_t)(h * 256 + b)) * 2048 + d * 32 + (ch & 1) * 16;
        ((uint4*)dst)[0] = tmp.q[0];
        ((uint4*)dst)[1] = tmp.q[1];
    }
    {
        int dd = tid & 63;
        int cc = tid >> 6;
#pragma unroll
        for (int u = 0; u < 2; ++u) {
            int c8 = cc + u * 4;
            float s = 0.f;
#pragma unroll
            for (int r = 0; r < 8; ++r) s += bf2f(t[dd][8 * c8 + r]);
            int C = (n0 >> 3) + c8;
            vt1[((size_t)((h * 32 + (C >> 5)) * DD + dd)) * 32 + (C & 31)] = f2bf(s * 0.125f);
        }
    }
    __syncthreads();

    // ---- Phase B: K convert -> blocked Kb + LDS ----
    {
        int row = tid >> 2, cs = (tid & 3) * 16;
        const float* src = k + ((size_t)(h * NTOK + n0 + row)) * DD + cs;
        float4 f0 = ((const float4*)src)[0], f1 = ((const float4*)src)[1];
        float4 f2 = ((const float4*)src)[2], f3 = ((const float4*)src)[3];
        union { unsigned short u[16]; uint4 q4[2]; } o;
        o.u[0] = f2bf(f0.x); o.u[1] = f2bf(f0.y); o.u[2] = f2bf(f0.z); o.u[3] = f2bf(f0.w);
        o.u[4] = f2bf(f1.x); o.u[5] = f2bf(f1.y); o.u[6] = f2bf(f1.z); o.u[7] = f2bf(f1.w);
        o.u[8] = f2bf(f2.x); o.u[9] = f2bf(f2.y); o.u[10] = f2bf(f2.z); o.u[11] = f2bf(f2.w);
        o.u[12] = f2bf(f3.x); o.u[13] = f2bf(f3.y); o.u[14] = f2bf(f3.z); o.u[15] = f2bf(f3.w);
        int grpb = (n0 >> 5) + (row >> 5);
        int kk = row & 31;
        int cw = ((kk >> 3) << 2) | (kk & 3);
        int qd = ((kk >> 2) & 1) * 2 + (cs >= 32 ? 1 : 0);
        int g0w = (cs & 31) >> 3;
        unsigned short* blk = Kb + ((size_t)(h * 256 + grpb)) * 2048 + qd * 512;
        *(uint4*)(blk + (g0w * 16 + cw) * 8) = o.q4[0];
        *(uint4*)(blk + ((g0w + 1) * 16 + cw) * 8) = o.q4[1];
#pragma unroll
        for (int j = 0; j < 16; ++j) t[cs + j][row] = o.u[j];
    }
    __syncthreads();
    {
        int dd = tid & 63;
        int cc = tid >> 6;
#pragma unroll
        for (int u = 0; u < 2; ++u) {
            int c8 = cc + u * 4;
            float s = 0.f;
#pragma unroll
            for (int r = 0; r < 8; ++r) s += bf2f(t[dd][8 * c8 + r]);
            int C = (n0 >> 3) + c8;
            k1[((size_t)(h * 1024 + C)) * DD + dd] = f2bf(s * 0.125f);
        }
    }
}

// ---------------- level-2 pool ----------------
__global__ __launch_bounds__(256) void pool2_b(const unsigned short* __restrict__ k1,
                                               const unsigned short* __restrict__ vt1,
                                               unsigned short* __restrict__ k2,
                                               unsigned short* __restrict__ vt2) {
    int tid = blockIdx.x * blockDim.x + threadIdx.x;
    int d = tid & 63;
    int c = (tid >> 6) & 127;
    int h = tid >> 13;
    const unsigned short* kp = k1 + ((size_t)(h * 1024 + c * 8)) * DD + d;
    float ks = 0.f;
#pragma unroll
    for (int r = 0; r < 8; ++r) ks += bf2f(kp[(size_t)r * DD]);
    const unsigned short* vp = vt1 + ((size_t)((h * 32 + (c >> 2)) * DD + d)) * 32 + 8 * (c & 3);
    union { unsigned short u[8]; uint4 q; } vv;
    vv.q = *(const uint4*)(const void*)vp;
    float vs = 0.f;
#pragma unroll
    for (int j = 0; j < 8; ++j) vs += bf2f(vv.u[j]);
    k2[((size_t)(h * 128 + c)) * DD + d] = f2bf(ks * 0.125f);
    vt2[((size_t)((h * 4 + (c >> 5)) * DD + d)) * 32 + (c & 31)] = f2bf(vs * 0.125f);
}

// ---------------- level-3 pool (16 real chunks, padded to 32) ----------------
__global__ __launch_bounds__(256) void pool3_b(const unsigned short* __restrict__ k2,
                                               const unsigned short* __restrict__ vt2,
                                               unsigned short* __restrict__ k3,
                                               unsigned short* __restrict__ vt3) {
    int tid = blockIdx.x * blockDim.x + threadIdx.x;
    int d = tid & 63;
    int c = (tid >> 6) & 31;
    int h = tid >> 11;
    float ks = 0.f, vs = 0.f;
    if (c < 16) {
        const unsigned short* kp = k2 + ((size_t)(h * 128 + c * 8)) * DD + d;
#pragma unroll
        for (int r = 0; r < 8; ++r) ks += bf2f(kp[(size_t)r * DD]);
        const unsigned short* vp = vt2 + ((size_t)((h * 4 + (c >> 2)) * DD + d)) * 32 + 8 * (c & 3);
        union { unsigned short u[8]; uint4 q; } vv;
        vv.q = *(const uint4*)(const void*)vp;
#pragma unroll
        for (int j = 0; j < 8; ++j) vs += bf2f(vv.u[j]);
        ks *= 0.125f; vs *= 0.125f;
    }
    k3[((size_t)(h * 32 + c)) * DD + d] = f2bf(ks);
    vt3[((size_t)(h * DD + d)) * 32 + c] = f2bf(vs);
}

// K+V fragments of one 32-key group
struct KV32 { bf16x8 k0, k1, k2, k3, v0, v1, v2, v3; };

// ---------------- one 32-key sub-group, 32 queries (2 tiles) ----------------
// Fixed-m streaming: no per-group max/ballot/rescale. INIT computes m once.
template<bool L0T, bool INIT>
__device__ __forceinline__ void sub32(
    int c0, int Qs, int lgS, float gp, float gps, float& m,
    const KV32& t, int g, int c,
    bf16x8 qa0, bf16x8 qa1, bf16x8 qb0, bf16x8 qb1,
    float& lA, float& lB, f32x4* oA, f32x4* oB)
{
    const int i_qA = Qs + c, i_qB = i_qA + 16;

    __builtin_amdgcn_s_setprio(1);
    f32x4 z = {0.f, 0.f, 0.f, 0.f};
    f32x4 sAA = MFMA(t.k1, qa1, MFMA(t.k0, qa0, z));
    f32x4 sAB = MFMA(t.k3, qa1, MFMA(t.k2, qa0, z));
    f32x4 sBA = MFMA(t.k1, qb1, MFMA(t.k0, qb0, z));
    f32x4 sBB = MFMA(t.k3, qb1, MFMA(t.k2, qb0, z));
    __builtin_amdgcn_s_setprio(0);

    const float negfbA = gps * (float)(8 * g) + gp * (float)((1 << lgS) - 1) - gp * (float)i_qA;
    const float negfbB = negfbA - 16.f * gp;
    float c0f = (float)c0;

    float svA[8], svB[8];
    bool fastA, fastB;
    if (L0T) {
        fastA = (c0 >= Qs - 112) && (c0 + 31 <= Qs);
        fastB = (c0 >= Qs - 96) && (c0 + 31 <= Qs + 16);
    } else {
        int numA = Qs - 128 - ((1 << lgS) - 1);
        int numB = numA + 16;
        fastA = (numA >= 0) && (c0 + 31 <= (numA >> lgS));
        fastB = (numB >= 0) && (c0 + 31 <= (numB >> lgS));
    }
    if (fastA) {
        float u0 = fmaf(gps, c0f, negfbA);
        svA[0] = sAA[0] + u0;
        svA[1] = sAA[1] + fmaf(gps, 1.f, u0);
        svA[2] = sAA[2] + fmaf(gps, 2.f, u0);
        svA[3] = sAA[3] + fmaf(gps, 3.f, u0);
        svA[4] = sAB[0] + fmaf(gps, 4.f, u0);
        svA[5] = sAB[1] + fmaf(gps, 5.f, u0);
        svA[6] = sAB[2] + fmaf(gps, 6.f, u0);
        svA[7] = sAB[3] + fmaf(gps, 7.f, u0);
    } else {
#pragma unroll
        for (int r = 0; r < 4; ++r) {
            int cA = c0 + 8 * g + r, cB = cA + 4;
            int jA = L0T ? cA : (((cA + 1) << lgS) - 1);
            int jB = L0T ? cB : (((cB + 1) << lgS) - 1);
            int dA = i_qA - jA, dB = i_qA - jB;
            bool aA = L0T ? ((unsigned)dA <= 127u) : (dA >= 128);
            bool aB = L0T ? ((unsigned)dB <= 127u) : (dB >= 128);
            svA[r]     = aA ? fmaf(-gp, (float)dA, sAA[r]) : NEGF;
            svA[r + 4] = aB ? fmaf(-gp, (float)dB, sAB[r]) : NEGF;
        }
    }
    if (fastB) {
        float u0 = fmaf(gps, c0f, negfbB);
        svB[0] = sBA[0] + u0;
        svB[1] = sBA[1] + fmaf(gps, 1.f, u0);
        svB[2] = sBA[2] + fmaf(gps, 2.f, u0);
        svB[3] = sBA[3] + fmaf(gps, 3.f, u0);
        svB[4] = sBB[0] + fmaf(gps, 4.f, u0);
        svB[5] = sBB[1] + fmaf(gps, 5.f, u0);
        svB[6] = sBB[2] + fmaf(gps, 6.f, u0);
        svB[7] = sBB[3] + fmaf(gps, 7.f, u0);
    } else {
#pragma unroll
        for (int r = 0; r < 4; ++r) {
            int cA = c0 + 8 * g + r, cB = cA + 4;
            int jA = L0T ? cA : (((cA + 1) << lgS) - 1);
            int jB = L0T ? cB : (((cB + 1) << lgS) - 1);
            int dA = i_qB - jA, dB = i_qB - jB;
            bool aA = L0T ? ((unsigned)dA <= 127u) : (dA >= 128);
            bool aB = L0T ? ((unsigned)dB <= 127u) : (dB >= 128);
            svB[r]     = aA ? fmaf(-gp, (float)dA, sBA[r]) : NEGF;
            svB[r + 4] = aB ? fmaf(-gp, (float)dB, sBB[r]) : NEGF;
        }
    }

    if (INIT) {
        float tm = fmaxf(
            fmaxf(fmaxf(fmaxf(svA[0], svA[1]), fmaxf(svA[2], svA[3])),
                  fmaxf(fmaxf(svA[4], svA[5]), fmaxf(svA[6], svA[7]))),
            fmaxf(fmaxf(fmaxf(svB[0], svB[1]), fmaxf(svB[2], svB[3])),
                  fmaxf(fmaxf(svB[4], svB[5]), fmaxf(svB[6], svB[7]))));
        tm = fmaxf(tm, __shfl_xor(tm, 1));
        tm = fmaxf(tm, __shfl_xor(tm, 2));
        tm = fmaxf(tm, __shfl_xor(tm, 4));
        tm = fmaxf(tm, __shfl_xor(tm, 8));
        tm = fmaxf(tm, __shfl_xor(tm, 16));
        tm = fmaxf(tm, __shfl_xor(tm, 32));
        m = tm;
    }

    union { unsigned u32[4]; bf16x8 v8; } pfA, pfB;
    {
        float p[8];
#pragma unroll
        for (int r = 0; r < 8; ++r) p[r] = EXP2(svA[r] - m);
        lA += ((p[0] + p[1]) + (p[2] + p[3])) + ((p[4] + p[5]) + (p[6] + p[7]));
#pragma unroll
        for (int j = 0; j < 4; ++j)
            asm("v_cvt_pk_bf16_f32 %0, %1, %2" : "=v"(pfA.u32[j]) : "v"(p[2 * j]), "v"(p[2 * j + 1]));
    }
    {
        float p[8];
#pragma unroll
        for (int r = 0; r < 8; ++r) p[r] = EXP2(svB[r] - m);
        lB += ((p[0] + p[1]) + (p[2] + p[3])) + ((p[4] + p[5]) + (p[6] + p[7]));
#pragma unroll
        for (int j = 0; j < 4; ++j)
            asm("v_cvt_pk_bf16_f32 %0, %1, %2" : "=v"(pfB.u32[j]) : "v"(p[2 * j]), "v"(p[2 * j + 1]));
    }

    __builtin_amdgcn_s_setprio(1);
    oA[0] = MFMA(t.v0, pfA.v8, oA[0]);
    oB[0] = MFMA(t.v0, pfB.v8, oB[0]);
    oA[1] = MFMA(t.v1, pfA.v8, oA[1]);
    oB[1] = MFMA(t.v1, pfB.v8, oB[1]);
    oA[2] = MFMA(t.v2, pfA.v8, oA[2]);
    oB[2] = MFMA(t.v2, pfB.v8, oB[2]);
    oA[3] = MFMA(t.v3, pfA.v8, oA[3]);
    oB[3] = MFMA(t.v3, pfB.v8, oB[3]);
    __builtin_amdgcn_s_setprio(0);
}

// ---------------- main attention: 1 wave/block (32 queries), LPT, blocked L0 K ----------------
__global__ __launch_bounds__(64, 2) void attn_mfma(
    const float* __restrict__ q, const unsigned short* __restrict__ Kb,
    const unsigned short* __restrict__ Vtb,
    const unsigned short* __restrict__ K1, const unsigned short* __restrict__ Vt1,
    const unsigned short* __restrict__ K2, const unsigned short* __restrict__ Vt2,
    const unsigned short* __restrict__ K3, const unsigned short* __restrict__ Vt3,
    const float* __restrict__ gam, float* __restrict__ out) {
    const int lane = threadIdx.x;
    const int h = blockIdx.x & 15;            // head->XCD pinning for L2 locality
    const int qpos = 255 - (blockIdx.x >> 4); // LPT: heaviest (late) positions dispatch first
    const int Qs = qpos << 5;
    const int g = lane >> 4;
    const int c = lane & 15;

    const float g0 = gam[0] * LOG2E, g1 = gam[1] * LOG2E;
    const float g2 = gam[2] * LOG2E, g3 = gam[3] * LOG2E;

    // L0: blocked K + blocked V
    const unsigned short* KbB = Kb + (size_t)h * 256 * 2048 + lane * 8;
    const unsigned short* VtH = Vtb + (size_t)h * 256 * 2048 + c * 32 + g * 8;
    // pooled levels: row-major K (key-permuted) + blocked V
    const size_t kperm = ((size_t)(8 * (c >> 2) + (c & 3))) * DD + g * 8;
    const unsigned short* K1H = K1 + (size_t)h * 1024 * DD + kperm;
    const unsigned short* V1H = Vt1 + (size_t)h * 32 * 2048 + c * 32 + g * 8;
    const unsigned short* K2H = K2 + (size_t)h * 128 * DD + kperm;
    const unsigned short* V2H = Vt2 + (size_t)h * 4 * 2048 + c * 32 + g * 8;
    const unsigned short* K3H = K3 + (size_t)h * 32 * DD + kperm;
    const unsigned short* V3H = Vt3 + (size_t)h * 2048 + c * 32 + g * 8;

    auto LOADKV0 = [&](int c0) -> KV32 {   // L0: fully blocked (8 contiguous 1KB loads)
        KV32 r;
        const unsigned short* ka = KbB + (size_t)(c0 >> 5) * 2048;
        r.k0 = *(const bf16x8*)(const void*)(ka);
        r.k1 = *(const bf16x8*)(const void*)(ka + 512);
        r.k2 = *(const bf16x8*)(const void*)(ka + 1024);
        r.k3 = *(const bf16x8*)(const void*)(ka + 1536);
        const unsigned short* va = VtH + (size_t)(c0 >> 5) * 2048;
        r.v0 = *(const bf16x8*)(const void*)(va);
        r.v1 = *(const bf16x8*)(const void*)(va + 512);
        r.v2 = *(const bf16x8*)(const void*)(va + 1024);
        r.v3 = *(const bf16x8*)(const void*)(va + 1536);
        return r;
    };
    auto LOADKV = [&](const unsigned short* Kh, const unsigned short* Vh, int c0) -> KV32 {
        KV32 r;
        const unsigned short* ka = Kh + (size_t)c0 * DD;
        r.k0 = *(const bf16x8*)(const void*)(ka);
        r.k1 = *(const bf16x8*)(const void*)(ka + 32);
        r.k2 = *(const bf16x8*)(const void*)(ka + 4 * DD);
        r.k3 = *(const bf16x8*)(const void*)(ka + 4 * DD + 32);
        const unsigned short* va = Vh + (size_t)(c0 >> 5) * 2048;
        r.v0 = *(const bf16x8*)(const void*)(va);
        r.v1 = *(const bf16x8*)(const void*)(va + 512);
        r.v2 = *(const bf16x8*)(const void*)(va + 1024);
        r.v3 = *(const bf16x8*)(const void*)(va + 1536);
        return r;
    };

    // Q fragments: fp32 load + scale + pack to bf16 in-kernel
    const float qsc = 0.125f * LOG2E;
    bf16x8 qa0, qa1, qb0, qb1;
    {
        const float* qrA = q + ((size_t)(h * NTOK + Qs + c)) * DD;
        const float* qrB = qrA + 16 * DD;
        float4 a0 = *(const float4*)(qrA + g * 8),      a1 = *(const float4*)(qrA + g * 8 + 4);
        float4 a2 = *(const float4*)(qrA + 32 + g * 8), a3 = *(const float4*)(qrA + 32 + g * 8 + 4);
        float4 b0 = *(const float4*)(qrB + g * 8),      b1 = *(const float4*)(qrB + g * 8 + 4);
        float4 b2 = *(const float4*)(qrB + 32 + g * 8), b3 = *(const float4*)(qrB + 32 + g * 8 + 4);
        union { unsigned u32[4]; bf16x8 v8; } p0, p1, p2, p3;
        asm("v_cvt_pk_bf16_f32 %0, %1, %2" : "=v"(p0.u32[0]) : "v"(a0.x * qsc), "v"(a0.y * qsc));
        asm("v_cvt_pk_bf16_f32 %0, %1, %2" : "=v"(p0.u32[1]) : "v"(a0.z * qsc), "v"(a0.w * qsc));
        asm("v_cvt_pk_bf16_f32 %0, %1, %2" : "=v"(p0.u32[2]) : "v"(a1.x * qsc), "v"(a1.y * qsc));
        asm("v_cvt_pk_bf16_f32 %0, %1, %2" : "=v"(p0.u32[3]) : "v"(a1.z * qsc), "v"(a1.w * qsc));
        asm("v_cvt_pk_bf16_f32 %0, %1, %2" : "=v"(p1.u32[0]) : "v"(a2.x * qsc), "v"(a2.y * qsc));
        asm("v_cvt_pk_bf16_f32 %0, %1, %2" : "=v"(p1.u32[1]) : "v"(a2.z * qsc), "v"(a2.w * qsc));
        asm("v_cvt_pk_bf16_f32 %0, %1, %2" : "=v"(p1.u32[2]) : "v"(a3.x * qsc), "v"(a3.y * qsc));
        asm("v_cvt_pk_bf16_f32 %0, %1, %2" : "=v"(p1.u32[3]) : "v"(a3.z * qsc), "v"(a3.w * qsc));
        asm("v_cvt_pk_bf16_f32 %0, %1, %2" : "=v"(p2.u32[0]) : "v"(b0.x * qsc), "v"(b0.y * qsc));
        asm("v_cvt_pk_bf16_f32 %0, %1, %2" : "=v"(p2.u32[1]) : "v"(b0.z * qsc), "v"(b0.w * qsc));
        asm("v_cvt_pk_bf16_f32 %0, %1, %2" : "=v"(p2.u32[2]) : "v"(b1.x * qsc), "v"(b1.y * qsc));
        asm("v_cvt_pk_bf16_f32 %0, %1, %2" : "=v"(p2.u32[3]) : "v"(b1.z * qsc), "v"(b1.w * qsc));
        asm("v_cvt_pk_bf16_f32 %0, %1, %2" : "=v"(p3.u32[0]) : "v"(b2.x * qsc), "v"(b2.y * qsc));
        asm("v_cvt_pk_bf16_f32 %0, %1, %2" : "=v"(p3.u32[1]) : "v"(b2.z * qsc), "v"(b2.w * qsc));
        asm("v_cvt_pk_bf16_f32 %0, %1, %2" : "=v"(p3.u32[2]) : "v"(b3.x * qsc), "v"(b3.y * qsc));
        asm("v_cvt_pk_bf16_f32 %0, %1, %2" : "=v"(p3.u32[3]) : "v"(b3.z * qsc), "v"(b3.w * qsc));
        qa0 = p0.v8; qa1 = p1.v8; qb0 = p2.v8; qb1 = p3.v8;
    }

    f32x4 oA[4], oB[4];
#pragma unroll
    for (int t = 0; t < 4; ++t) { oA[t] = (f32x4){0.f,0.f,0.f,0.f}; oB[t] = (f32x4){0.f,0.f,0.f,0.f}; }
    float m = NEGF, lA = 0.f, lB = 0.f;

    // ---- level 0, diagonal group (INIT m) ----
    {
        KV32 t = LOADKV0(Qs);
        sub32<true, true>(Qs, Qs, 0, g0, g0, m, t, g, c, qa0, qa1, qb0, qb1, lA, lB, oA, oB);
    }
    // ---- level 0, remaining window, paired 64-key iterations ----
    {
        int lo0 = Qs - 127; if (lo0 < 0) lo0 = 0; lo0 &= ~31;
        int c0 = Qs - 64;
        while (c0 >= lo0) {
            KV32 a = LOADKV0(c0 + 32);
            KV32 b = LOADKV0(c0);
            sub32<true, false>(c0 + 32, Qs, 0, g0, g0, m, a, g, c, qa0, qa1, qb0, qb1, lA, lB, oA, oB);
            sub32<true, false>(c0,      Qs, 0, g0, g0, m, b, g, c, qa0, qa1, qb0, qb1, lA, lB, oA, oB);
            c0 -= 64;
        }
        if (c0 + 32 >= lo0) {
            KV32 a = LOADKV0(c0 + 32);
            sub32<true, false>(c0 + 32, Qs, 0, g0, g0, m, a, g, c, qa0, qa1, qb0, qb1, lA, lB, oA, oB);
        }
    }
    // ---- level 1: 64-key iterations, truncated at CUT1 tokens ----
    {
        int cm = Qs - 104;                 // (Qs+31)-128-7
        if (cm >= 0) {
            int top = (cm >> 3) & ~31;
            int lo = Qs - CUT1;
            lo = (lo <= 0) ? 0 : ((lo >> 3) & ~31);
            int c0 = top;
            while (c0 - 32 >= lo) {
                KV32 a = LOADKV(K1H, V1H, c0);
                KV32 b = LOADKV(K1H, V1H, c0 - 32);
                sub32<false, false>(c0,      Qs, 3, g1, g1 * 8.f, m, a, g, c, qa0, qa1, qb0, qb1, lA, lB, oA, oB);
                sub32<false, false>(c0 - 32, Qs, 3, g1, g1 * 8.f, m, b, g, c, qa0, qa1, qb0, qb1, lA, lB, oA, oB);
                c0 -= 64;
            }
            if (c0 >= lo) {
                KV32 a = LOADKV(K1H, V1H, c0);
                sub32<false, false>(c0, Qs, 3, g1, g1 * 8.f, m, a, g, c, qa0, qa1, qb0, qb1, lA, lB, oA, oB);
            }
        }
    }
    // ---- level 2: 64-key iterations (<=2) ----
    {
        int cm = Qs - 160;                 // (Qs+31)-128-63
        if (cm >= 0) {
            for (int c0 = ((cm / 64) & ~63); c0 >= 0; c0 -= 64) {
                KV32 a = LOADKV(K2H, V2H, c0 + 32);
                KV32 b = LOADKV(K2H, V2H, c0);
                sub32<false, false>(c0 + 32, Qs, 6, g2, g2 * 64.f, m, a, g, c, qa0, qa1, qb0, qb1, lA, lB, oA, oB);
                sub32<false, false>(c0,      Qs, 6, g2, g2 * 64.f, m, b, g, c, qa0, qa1, qb0, qb1, lA, lB, oA, oB);
            }
        }
    }
    // ---- level 3: single 32-chunk group ----
    {
        if (Qs >= 608) {
            KV32 t = LOADKV(K3H, V3H, 0);
            sub32<false, false>(0, Qs, 9, g3, g3 * 512.f, m, t, g, c, qa0, qa1, qb0, qb1, lA, lB, oA, oB);
        }
    }

    // final l reduce over the 4 g-lanes of each query column
    float ltA = lA + __shfl_xor(lA, 16); ltA += __shfl_xor(ltA, 32);
    float ltB = lB + __shfl_xor(lB, 16); ltB += __shfl_xor(ltB, 32);
    float invA = 1.0f / fmaxf(ltA, 1e-8f);
    float invB = 1.0f / fmaxf(ltB, 1e-8f);

    float* orowA = out + ((size_t)(h * NTOK + Qs + c)) * DD;
    float* orowB = orowA + 16 * DD;
#pragma unroll
    for (int db = 0; db < 4; ++db) {
        float4 x;
        x.x = oA[db][0] * invA; x.y = oA[db][1] * invA;
        x.z = oA[db][2] * invA; x.w = oA[db][3] * invA;
        *(float4*)(orowA + db * 16 + 4 * g) = x;
        float4 y;
        y.x = oB[db][0] * invB; y.y = oB[db][1] * invB;
        y.z = oB[db][2] * invB; y.w = oB[db][3] * invB;
        *(float4*)(orowB + db * 16 + 4 * g) = y;
    }
}

extern "C" void kernel_launch(void* const* d_in, const int* in_sizes, int n_in,
                              void* d_out, int out_size, void* d_ws, size_t ws_size,
                              hipStream_t stream) {
    const float* q = (const float*)d_in[0];
    const float* k = (const float*)d_in[1];
    const float* v = (const float*)d_in[2];
    const float* gam = (const float*)d_in[3];
    float* out = (float*)d_out;

    char* w = (char*)d_ws;
    const size_t bigN = (size_t)NH * NTOK * DD * sizeof(unsigned short);
    unsigned short* Kbuf = (unsigned short*)w;  w += bigN;
    unsigned short* Vtb  = (unsigned short*)w;  w += bigN;
    unsigned short* K1   = (unsigned short*)w;  w += (size_t)NH * 1024 * DD * 2;
    unsigned short* Vt1  = (unsigned short*)w;  w += (size_t)NH * 1024 * DD * 2;
    unsigned short* K2   = (unsigned short*)w;  w += (size_t)NH * 128 * DD * 2;
    unsigned short* Vt2  = (unsigned short*)w;  w += (size_t)NH * 128 * DD * 2;
    unsigned short* K3   = (unsigned short*)w;  w += (size_t)NH * 32 * DD * 2;
    unsigned short* Vt3  = (unsigned short*)w;  w += (size_t)NH * 32 * DD * 2;

    prep_kv1<<<NH * (NTOK / 64), 256, 0, stream>>>(k, v, Kbuf, Vtb, K1, Vt1);
    pool2_b<<<NH * 128 * DD / 256, 256, 0, stream>>>(K1, Vt1, K2, Vt2);
    pool3_b<<<NH * 32 * DD / 256, 256, 0, stream>>>(K2, Vt2, K3, Vt3);

    attn_mfma<<<NH * 256, 64, 0, stream>>>(q, Kbuf, Vtb, K1, Vt1, K2, Vt2, K3, Vt3, gam, out);
}